// Round 4
// baseline (736.424 us; speedup 1.0000x reference)
//
#include <hip/hip_runtime.h>
#include <hip/hip_bf16.h>
#include <math.h>

constexpr int R_ = 4096;
constexpr int N_ = 128;

typedef __attribute__((ext_vector_type(8))) short short8;
typedef __attribute__((ext_vector_type(4))) float f32x4;
typedef __attribute__((ext_vector_type(16))) float f32x16;

#define MFMA32(a, b, c) __builtin_amdgcn_mfma_f32_32x32x16_bf16(a, b, c, 0, 0, 0)

__device__ __forceinline__ unsigned short f2bf(float f) {
    unsigned int u = __float_as_uint(f);
    u += 0x7fffu + ((u >> 16) & 1u);   // RNE
    return (unsigned short)(u >> 16);
}
__device__ __forceinline__ float bf2f(unsigned short h) {
    return __uint_as_float(((unsigned int)h) << 16);
}

// ---------------------------------------------------------------------------
// Weight prep: bf16, transposed [n][k], LINEAR (no swizzle — consumed by
// coalesced global loads, not LDS).  Element i maps 1:1 to dst i:
//   [0,16384):      W0t  n in [0,256), k in [0,64)  (k=63 zero pad)
//   [16384,81920):  W1t  n in [0,256), k in [0,256)
//   [81920,147456): W2t  n in [0,256), k in [0,256)
//   [147456,180224):Wc1t n in [0,128), k in [0,256)
// ---------------------------------------------------------------------------
__global__ __launch_bounds__(256) void prep_weights(
    const float* __restrict__ W0, const float* __restrict__ W1,
    const float* __restrict__ W2, const float* __restrict__ Wc1,
    unsigned short* __restrict__ out)
{
    int i = blockIdx.x * 256 + threadIdx.x;
    if (i >= 180224) return;
    float val;
    if (i < 16384) {
        int n = i >> 6, k = i & 63;
        val = (k < 63) ? W0[k * 256 + n] : 0.f;
    } else if (i < 81920) {
        int e = i - 16384, n = e >> 8, k = e & 255;
        val = W1[k * 256 + n];
    } else if (i < 147456) {
        int e = i - 81920, n = e >> 8, k = e & 255;
        val = W2[k * 256 + n];
    } else {
        int e = i - 147456, n = e >> 8, k = e & 255;
        val = Wc1[k * 128 + n];
    }
    out[i] = f2bf(val);
}

// One K=256 layer: B-frags (acts) from LDS once, A (weights) streamed from
// global (L1/L2-resident), relu+pack epilogue back to s_act in place.
template <int NTW>
__device__ __forceinline__ void layer_k256(
    const unsigned char* __restrict__ wbase,   // global, [n][256] bf16
    const float* __restrict__ bias,            // LDS, N floats
    int cgrp, int ls, int hi, int swz, unsigned char* __restrict__ wp)
{
    short8 B[16];
    #pragma unroll
    for (int ks = 0; ks < 16; ++ks)
        B[ks] = *(const short8*)(wp + ((32 * ks + 16 * hi) ^ swz));
    __syncthreads();   // all input reads done before any epilogue write
    #pragma unroll
    for (int ti = 0; ti < NTW; ++ti) {
        const int ct = cgrp * NTW + ti;
        const unsigned char* ap = wbase + (ct * 32 + ls) * 512 + 16 * hi;
        f32x16 acc;
        #pragma unroll
        for (int g = 0; g < 4; ++g) {
            f32x4 bv = *(const f32x4*)&bias[ct * 32 + 4 * hi + 8 * g];
            acc[4*g+0] = bv[0]; acc[4*g+1] = bv[1];
            acc[4*g+2] = bv[2]; acc[4*g+3] = bv[3];
        }
        #pragma unroll
        for (int q = 0; q < 4; ++q) {
            short8 A0 = *(const short8*)(ap + 128 * q);
            short8 A1 = *(const short8*)(ap + 128 * q + 32);
            short8 A2 = *(const short8*)(ap + 128 * q + 64);
            short8 A3 = *(const short8*)(ap + 128 * q + 96);
            acc = MFMA32(A0, B[4*q+0], acc);
            acc = MFMA32(A1, B[4*q+1], acc);
            acc = MFMA32(A2, B[4*q+2], acc);
            acc = MFMA32(A3, B[4*q+3], acc);
        }
        #pragma unroll
        for (int g = 0; g < 4; ++g) {
            int n = ct * 32 + 4 * hi + 8 * g;
            unsigned long long pk =
                  (unsigned long long)f2bf(fmaxf(acc[4*g+0], 0.f))
                | ((unsigned long long)f2bf(fmaxf(acc[4*g+1], 0.f)) << 16)
                | ((unsigned long long)f2bf(fmaxf(acc[4*g+2], 0.f)) << 32)
                | ((unsigned long long)f2bf(fmaxf(acc[4*g+3], 0.f)) << 48);
            *(unsigned long long*)(wp + ((2 * n) ^ swz)) = pk;
        }
    }
    __syncthreads();   // epilogue writes visible to next layer's B reads
}

// ---------------------------------------------------------------------------
// Fused NeRF kernel: 1 block = 1 ray (128 samples), 512 threads = 8 waves.
// Wave = (st = wave&3: 32-row sample tile, cgrp = wave>>2: col group).
// LDS ~76 KB -> 2 blocks/CU.  Weights direct from global (L1/L2).
// ---------------------------------------------------------------------------
__global__ __launch_bounds__(512, 4) void nerf_kernel(
    const float* __restrict__ ray, const float* __restrict__ t,
    const float* __restrict__ b0g, const float* __restrict__ b1g,
    const float* __restrict__ b2g,
    const float* __restrict__ Wsg, const float* __restrict__ bsg,
    const float* __restrict__ Wc1g, const float* __restrict__ bc1g,
    const float* __restrict__ Wc2g, const float* __restrict__ bc2g,
    const unsigned char* __restrict__ wt,
    float* __restrict__ rgb_out, float* __restrict__ wi_out)
{
    __shared__ __align__(16) unsigned char s_act[128 * 512];   // 64 KB bf16 acts
    __shared__ __align__(16) float s_bias[896];  // b0|b1|b2|decont(128)
    __shared__ float s_ws[256];
    __shared__ float s_wc2[384];
    __shared__ float s_sigma[128];
    __shared__ float s_color[384];
    __shared__ float s_de[27];
    __shared__ float s_od[6];
    __shared__ float s_t[129];
    __shared__ float s_ts[129];
    __shared__ float s_sdt[128];
    __shared__ float s_cum[128];
    __shared__ float s_wi[128];

    const int tid  = threadIdx.x;
    const int wave = tid >> 6;
    const int lane = tid & 63;
    const int r    = blockIdx.x;

    const int st   = wave & 3;
    const int cgrp = wave >> 2;
    const int ls   = lane & 31;
    const int hi   = lane >> 5;
    const int row  = st * 32 + ls;
    const int swz  = (ls & 7) << 4;
    unsigned char* const wp = s_act + row * 512;

    if (tid < 6) s_od[tid] = ray[r * 6 + tid];
    __syncthreads();
    const float d0 = s_od[3], d1 = s_od[4], d2 = s_od[5];

    // ---- posenc(x,10): 1 sinf/cosf + 9 doublings per coord; col 63 = 0 ----
    {
        const int grp = tid >> 7, p = tid & 127;
        const int sw = (p & 7) << 4;
        unsigned char* wp0 = s_act + p * 512;
        if (grp < 3) {
            float tv = t[r * 129 + 1 + p];
            float x = s_od[grp] + tv * s_od[grp + 3];
            *(unsigned short*)(wp0 + ((2 * grp) ^ sw)) = f2bf(x);
            float sv = sinf(x), cv = cosf(x);
            #pragma unroll
            for (int l = 0; l < 10; ++l) {
                *(unsigned short*)(wp0 + ((2 * (3 + 6 * l + grp)) ^ sw)) = f2bf(sv);
                *(unsigned short*)(wp0 + ((2 * (6 + 6 * l + grp)) ^ sw)) = f2bf(cv);
                float ns = 2.f * sv * cv;
                float nc = 1.f - 2.f * sv * sv;
                sv = ns; cv = nc;
            }
        } else {
            *(unsigned short*)(wp0 + (126 ^ sw)) = 0;
        }
    }
    // de = posenc(d,4)
    if (tid < 27) {
        int f = tid; float v;
        if (f < 3) v = (f == 0) ? d0 : ((f == 1) ? d1 : d2);
        else {
            int q = f - 3, l = q / 6, rm = q % 6, c = rm % 3;
            float dc = (c == 0) ? d0 : ((c == 1) ? d1 : d2);
            float a = dc * (float)(1 << l);
            v = (rm < 3) ? sinf(a) : cosf(a);
        }
        s_de[f] = v;
    }
    // head weights + biases
    if (tid < 256) { s_bias[tid] = b0g[tid]; s_bias[512 + tid] = b2g[tid]; }
    else           { s_bias[tid] = b1g[tid - 256]; }   // s_bias[256..511] = b1
    if (tid < 256) s_ws[tid]  = Wsg[tid];
    if (tid < 384) s_wc2[tid] = Wc2g[tid];
    __syncthreads();

    // decont[j] = bc1[j] + sum_k de[k]*Wc1[256+k][j]  -> s_bias[768+j]
    if (tid < 128) {
        float acc = bc1g[tid];
        for (int k = 0; k < 27; ++k)
            acc = fmaf(s_de[k], Wc1g[(256 + k) * 128 + tid], acc);
        s_bias[768 + tid] = acc;
    }

    // ======================= Layer 0 (K=64, row=128B) ======================
    {
        short8 B0[4];
        #pragma unroll
        for (int ks = 0; ks < 4; ++ks)
            B0[ks] = *(const short8*)(wp + ((32 * ks + 16 * hi) ^ swz));
        __syncthreads();   // posenc reads done (and decont written)
        #pragma unroll
        for (int ti = 0; ti < 4; ++ti) {
            const int ct = cgrp * 4 + ti;
            const unsigned char* ap = wt + (ct * 32 + ls) * 128 + 16 * hi;
            f32x16 acc;
            #pragma unroll
            for (int g = 0; g < 4; ++g) {
                f32x4 bv = *(const f32x4*)&s_bias[ct * 32 + 4 * hi + 8 * g];
                acc[4*g+0] = bv[0]; acc[4*g+1] = bv[1];
                acc[4*g+2] = bv[2]; acc[4*g+3] = bv[3];
            }
            #pragma unroll
            for (int ks = 0; ks < 4; ++ks) {
                short8 A = *(const short8*)(ap + 32 * ks);
                acc = MFMA32(A, B0[ks], acc);
            }
            #pragma unroll
            for (int g = 0; g < 4; ++g) {
                int n = ct * 32 + 4 * hi + 8 * g;
                unsigned long long pk =
                      (unsigned long long)f2bf(fmaxf(acc[4*g+0], 0.f))
                    | ((unsigned long long)f2bf(fmaxf(acc[4*g+1], 0.f)) << 16)
                    | ((unsigned long long)f2bf(fmaxf(acc[4*g+2], 0.f)) << 32)
                    | ((unsigned long long)f2bf(fmaxf(acc[4*g+3], 0.f)) << 48);
                *(unsigned long long*)(wp + ((2 * n) ^ swz)) = pk;
            }
        }
        __syncthreads();
    }

    // ============ Layers 1, 2 (256->256), weights direct from L2 ===========
    layer_k256<4>(wt + 32768,  s_bias + 256, cgrp, ls, hi, swz, wp);
    layer_k256<4>(wt + 163840, s_bias + 512, cgrp, ls, hi, swz, wp);

    // ---- sigma head: softplus(h3 @ Ws + bs); reads h3 before Wc1 clobbers --
    {
        const int p = tid >> 2, q = tid & 3;
        const int pswz = (p & 7) << 4;
        float sum = 0.f;
        #pragma unroll
        for (int g = 0; g < 8; ++g) {
            short8 h = *(const short8*)(s_act + p * 512 + ((q * 128 + g * 16) ^ pswz));
            int kb = q * 64 + g * 8;
            #pragma unroll
            for (int j = 0; j < 8; ++j)
                sum = fmaf(bf2f((unsigned short)h[j]), s_ws[kb + j], sum);
        }
        sum += __shfl_xor(sum, 1);
        sum += __shfl_xor(sum, 2);
        if (q == 0) {
            float x = sum + bsg[0];
            s_sigma[p] = fmaxf(x, 0.f) + log1pf(expf(-fabsf(x)));
        }
    }

    // ================= Wc1 (256->128), bias = decont ========================
    layer_k256<2>(wt + 294912, s_bias + 768, cgrp, ls, hi, swz, wp);

    // ================= color head: sigmoid(hc @ Wc2 + bc2) ==================
    {
        const int p = tid >> 2, q = tid & 3;
        const int pswz = (p & 7) << 4;
        float c0 = 0.f, c1 = 0.f, c2 = 0.f;
        #pragma unroll
        for (int g = 0; g < 4; ++g) {
            short8 h = *(const short8*)(s_act + p * 512 + ((q * 64 + g * 16) ^ pswz));
            int kb = q * 32 + g * 8;
            #pragma unroll
            for (int j = 0; j < 8; ++j) {
                float hv = bf2f((unsigned short)h[j]);
                c0 = fmaf(hv, s_wc2[(kb + j) * 3 + 0], c0);
                c1 = fmaf(hv, s_wc2[(kb + j) * 3 + 1], c1);
                c2 = fmaf(hv, s_wc2[(kb + j) * 3 + 2], c2);
            }
        }
        c0 += __shfl_xor(c0, 1); c0 += __shfl_xor(c0, 2);
        c1 += __shfl_xor(c1, 1); c1 += __shfl_xor(c1, 2);
        c2 += __shfl_xor(c2, 1); c2 += __shfl_xor(c2, 2);
        if (q == 0) {
            s_color[p * 3 + 0] = 1.f / (1.f + expf(-(c0 + bc2g[0])));
            s_color[p * 3 + 1] = 1.f / (1.f + expf(-(c1 + bc2g[1])));
            s_color[p * 3 + 2] = 1.f / (1.f + expf(-(c2 + bc2g[2])));
        }
    }
    __syncthreads();

    // ======================= render (sort/scan/composite) ===================
    if (tid < 129) s_t[tid] = t[r * 129 + tid];
    __syncthreads();
    if (tid < 129) {
        float v = s_t[tid];
        int rank = 0;
        for (int j = 0; j < 129; ++j) {
            float u = s_t[j];
            rank += (u < v) || (u == v && j < tid);
        }
        s_ts[rank] = v;
    }
    __syncthreads();
    if (tid < 128) {
        float dt = s_ts[tid + 1] - s_ts[tid];
        float sd = s_sigma[tid] * dt;
        s_sdt[tid] = sd;
        s_cum[tid] = sd;
    }
    __syncthreads();
    for (int off = 1; off < 128; off <<= 1) {
        float add = (tid < 128 && tid >= off) ? s_cum[tid - off] : 0.f;
        __syncthreads();
        if (tid < 128) s_cum[tid] += add;
        __syncthreads();
    }
    if (tid < 128) {
        float Ti = (tid == 0) ? 1.f : expf(-s_cum[tid - 1]);
        float alpha = 1.f - expf(-s_sdt[tid]);
        float w = Ti * alpha;
        s_wi[tid] = w;
        wi_out[r * 128 + tid] = w;
    }
    __syncthreads();
    if (tid < 3) {
        float acc = 0.f;
        for (int i = 0; i < 128; ++i)
            acc = fmaf(s_wi[i], s_color[i * 3 + tid], acc);
        rgb_out[r * 3 + tid] = acc;
    }
}

extern "C" void kernel_launch(void* const* d_in, const int* in_sizes, int n_in,
                              void* d_out, int out_size, void* d_ws, size_t ws_size,
                              hipStream_t stream)
{
    const float* ray = (const float*)d_in[0];
    const float* t   = (const float*)d_in[1];
    const float* W0  = (const float*)d_in[2];
    const float* b0  = (const float*)d_in[3];
    const float* W1  = (const float*)d_in[4];
    const float* b1  = (const float*)d_in[5];
    const float* W2  = (const float*)d_in[6];
    const float* b2  = (const float*)d_in[7];
    const float* Ws  = (const float*)d_in[8];
    const float* bs  = (const float*)d_in[9];
    const float* Wc1 = (const float*)d_in[10];
    const float* bc1 = (const float*)d_in[11];
    const float* Wc2 = (const float*)d_in[12];
    const float* bc2 = (const float*)d_in[13];

    unsigned short* wt = (unsigned short*)d_ws;   // 360448 B weight image
    float* rgb_out = (float*)d_out;               // R*3
    float* wi_out  = rgb_out + R_ * 3;            // R*128

    hipLaunchKernelGGL(prep_weights, dim3(704), dim3(256), 0, stream,
                       W0, W1, W2, Wc1, wt);
    hipLaunchKernelGGL(nerf_kernel, dim3(R_), dim3(512), 0, stream,
                       ray, t, b0, b1, b2, Ws, bs, Wc1, bc1, Wc2, bc2,
                       (const unsigned char*)wt, rgb_out, wi_out);
}

// Round 6
// 351.976 us; speedup vs baseline: 2.0923x; 2.0923x over previous
//
#include <hip/hip_runtime.h>
#include <hip/hip_bf16.h>
#include <math.h>

constexpr int R_ = 4096;

typedef __attribute__((ext_vector_type(8))) short short8;
typedef __attribute__((ext_vector_type(4))) float f32x4;
typedef __attribute__((ext_vector_type(16))) float f32x16;
typedef __attribute__((ext_vector_type(2))) unsigned int uint2v;

#define MFMA32(a, b, c) __builtin_amdgcn_mfma_f32_32x32x16_bf16(a, b, c, 0, 0, 0)

union U4 { unsigned int u[4]; short8 s8; };

__device__ __forceinline__ unsigned short f2bf(float f) {
    unsigned int u = __float_as_uint(f);
    u += 0x7fffu + ((u >> 16) & 1u);   // RNE
    return (unsigned short)(u >> 16);
}

__device__ __forceinline__ unsigned int cvtpk(float lo, float hi) {
    unsigned int d;
    asm("v_cvt_pk_bf16_f32 %0, %1, %2" : "=v"(d) : "v"(lo), "v"(hi));
    return d;
}
// permlane32_swap via the gfx950 builtin (NOT raw asm: the post-RA hazard
// recognizer must see this op to insert VALU->permlane waitstates; raw asm
// caused timing-dependent corruption under graph replay in round 5).
__device__ __forceinline__ void swap32(unsigned int& a, unsigned int& b) {
    uint2v r = __builtin_amdgcn_permlane32_swap(a, b, false, false);
    a = r[0]; b = r[1];
}

// Build next-layer B-frag slice from relu'd fp32 accs (two reg-groups).
__device__ __forceinline__ short8 pack_half(float a0, float a1, float a2, float a3,
                                            float b0, float b1, float b2, float b3) {
    unsigned int x0 = cvtpk(a0, a1), x1 = cvtpk(a2, a3);
    unsigned int x2 = cvtpk(b0, b1), x3 = cvtpk(b2, b3);
    swap32(x0, x2);
    swap32(x1, x3);
    U4 t; t.u[0] = x0; t.u[1] = x1; t.u[2] = x2; t.u[3] = x3;
    return t.s8;
}

// ---------------------------------------------------------------------------
// Weight prep: bf16 fragments in MFMA order. For region with KS k-slices:
//   dst elem = base + ((ct*KS + ks)*64 + lane)*8 + j,
//   lane = hi*32+ls:  n = ct*32+ls,  k = ks*16 + hi*8 + j.
// Regions (elem offsets): L0 @0 (KS=4, 8 ct), L1 @16384 (KS=16, 8 ct),
//   L2 @81920 (KS=16, 8 ct), Wc1 @147456 (KS=16, 4 ct).
// ---------------------------------------------------------------------------
__global__ __launch_bounds__(256) void prep_weights(
    const float* __restrict__ W0, const float* __restrict__ W1,
    const float* __restrict__ W2, const float* __restrict__ Wc1,
    unsigned short* __restrict__ out)
{
    int i = blockIdx.x * 256 + threadIdx.x;
    if (i >= 180224) return;
    float val;
    if (i < 16384) {
        int j = i & 7, l = (i >> 3) & 63, q = i >> 9;          // q = ct*4+ks
        int ks = q & 3, ct = q >> 2, ls = l & 31, hi = l >> 5;
        int n = ct * 32 + ls, k = ks * 16 + hi * 8 + j;
        val = (k < 63) ? W0[k * 256 + n] : 0.f;
    } else if (i < 81920) {
        int e = i - 16384;
        int j = e & 7, l = (e >> 3) & 63, q = e >> 9;          // q = ct*16+ks
        int ks = q & 15, ct = q >> 4, ls = l & 31, hi = l >> 5;
        int n = ct * 32 + ls, k = ks * 16 + hi * 8 + j;
        val = W1[k * 256 + n];
    } else if (i < 147456) {
        int e = i - 81920;
        int j = e & 7, l = (e >> 3) & 63, q = e >> 9;
        int ks = q & 15, ct = q >> 4, ls = l & 31, hi = l >> 5;
        int n = ct * 32 + ls, k = ks * 16 + hi * 8 + j;
        val = W2[k * 256 + n];
    } else {
        int e = i - 147456;
        int j = e & 7, l = (e >> 3) & 63, q = e >> 9;          // ct<4
        int ks = q & 15, ct = q >> 4, ls = l & 31, hi = l >> 5;
        int n = ct * 32 + ls, k = ks * 16 + hi * 8 + j;
        val = Wc1[k * 128 + n];
    }
    out[i] = f2bf(val);
}

// One K=256 layer over NT 32-col tiles; acts in registers, weights from global.
template <int NT, bool DO_SIGMA, bool DO_PACK, bool DO_COLOR>
__device__ __forceinline__ void mlp_layer(
    const unsigned short* __restrict__ wbase,
    const float* __restrict__ biasv,     // LDS
    const float* __restrict__ wsv,       // LDS (sigma) or null
    const float* __restrict__ wc2R,      // LDS [c][128] or null
    int lane, int hi,
    const short8 (&Bin)[16], short8 (&Bout)[16],
    float& sp, float& c0, float& c1, float& c2)
{
    #pragma unroll
    for (int ct = 0; ct < NT; ++ct) {
        const short8* __restrict__ ap = (const short8*)wbase + (ct * 16) * 64 + lane;
        f32x16 acc;
        #pragma unroll
        for (int g = 0; g < 4; ++g) {
            f32x4 bv = *(const f32x4*)&biasv[ct * 32 + 4 * hi + 8 * g];
            acc[4*g+0] = bv[0]; acc[4*g+1] = bv[1];
            acc[4*g+2] = bv[2]; acc[4*g+3] = bv[3];
        }
        #pragma unroll
        for (int ks = 0; ks < 16; ++ks)
            acc = MFMA32(ap[ks * 64], Bin[ks], acc);
        float rr[16];
        #pragma unroll
        for (int i = 0; i < 16; ++i) rr[i] = fmaxf(acc[i], 0.f);
        if constexpr (DO_SIGMA) {
            #pragma unroll
            for (int g = 0; g < 4; ++g) {
                f32x4 wv = *(const f32x4*)&wsv[ct * 32 + 4 * hi + 8 * g];
                sp = fmaf(rr[4*g+0], wv[0], sp);
                sp = fmaf(rr[4*g+1], wv[1], sp);
                sp = fmaf(rr[4*g+2], wv[2], sp);
                sp = fmaf(rr[4*g+3], wv[3], sp);
            }
        }
        if constexpr (DO_COLOR) {
            #pragma unroll
            for (int g = 0; g < 4; ++g) {
                int nb = ct * 32 + 4 * hi + 8 * g;
                f32x4 w0 = *(const f32x4*)&wc2R[0 * 128 + nb];
                f32x4 w1 = *(const f32x4*)&wc2R[1 * 128 + nb];
                f32x4 w2 = *(const f32x4*)&wc2R[2 * 128 + nb];
                #pragma unroll
                for (int i = 0; i < 4; ++i) {
                    c0 = fmaf(rr[4*g+i], w0[i], c0);
                    c1 = fmaf(rr[4*g+i], w1[i], c1);
                    c2 = fmaf(rr[4*g+i], w2[i], c2);
                }
            }
        }
        if constexpr (DO_PACK) {
            Bout[2*ct+0] = pack_half(rr[0], rr[1], rr[2],  rr[3],
                                     rr[4], rr[5], rr[6],  rr[7]);
            Bout[2*ct+1] = pack_half(rr[8], rr[9], rr[10], rr[11],
                                     rr[12], rr[13], rr[14], rr[15]);
        }
    }
}

// ---------------------------------------------------------------------------
// Fused NeRF: 1 block = 1 ray, 256 threads = 4 waves, wave = 32 samples.
// Acts live in registers across all layers; MLP phase has NO barriers.
// ---------------------------------------------------------------------------
__global__ __launch_bounds__(256, 2) void nerf_kernel(
    const float* __restrict__ ray, const float* __restrict__ t,
    const float* __restrict__ b0g, const float* __restrict__ b1g,
    const float* __restrict__ b2g,
    const float* __restrict__ Wsg, const float* __restrict__ bsg,
    const float* __restrict__ Wc1g, const float* __restrict__ bc1g,
    const float* __restrict__ Wc2g, const float* __restrict__ bc2g,
    const unsigned short* __restrict__ wt,
    float* __restrict__ rgb_out, float* __restrict__ wi_out)
{
    __shared__ __align__(16) unsigned char s_xe[128 * 128];  // 16 KB posenc
    __shared__ __align__(16) float s_bias[896];  // b0|b1|b2|decont
    __shared__ __align__(16) float s_ws[256];
    __shared__ __align__(16) float s_wc2R[384];  // [c][128]
    __shared__ float s_sigma[128];
    __shared__ float s_color[384];
    __shared__ float s_de[27];
    __shared__ float s_od[6];
    __shared__ float s_t[129];
    __shared__ float s_ts[129];
    __shared__ float s_sdt[128];
    __shared__ float s_cum[128];
    __shared__ float s_wi[128];

    const int tid  = threadIdx.x;
    const int wv   = tid >> 6;
    const int lane = tid & 63;
    const int r    = blockIdx.x;
    const int ls   = lane & 31;
    const int hi   = lane >> 5;
    const int row  = wv * 32 + ls;      // this wave-lane's sample
    const int sw   = (ls & 7) << 4;

    if (tid < 6) s_od[tid] = ray[r * 6 + tid];
    __syncthreads();
    const float d0 = s_od[3], d1 = s_od[4], d2 = s_od[5];

    // ---- fills: biases, head weights, de, t ----
    s_bias[tid] = b0g[tid];
    s_bias[256 + tid] = b1g[tid];
    s_bias[512 + tid] = b2g[tid];
    s_ws[tid] = Wsg[tid];
    for (int i = tid; i < 384; i += 256) {
        int c = i >> 7, n = i & 127;
        s_wc2R[i] = Wc2g[n * 3 + c];
    }
    if (tid < 129) s_t[tid] = t[r * 129 + tid];
    if (tid < 27) {
        int f = tid; float v;
        if (f < 3) v = (f == 0) ? d0 : ((f == 1) ? d1 : d2);
        else {
            int q = f - 3, l = q / 6, rm = q % 6, c = rm % 3;
            float dc = (c == 0) ? d0 : ((c == 1) ? d1 : d2);
            float a = dc * (float)(1 << l);
            v = (rm < 3) ? sinf(a) : cosf(a);
        }
        s_de[f] = v;
    }
    __syncthreads();

    // ---- posenc(x,10) into s_xe (rows=sample, 64 bf16, XOR-swizzled) ------
    {
        const int p = tid & 127;
        const int psw = (p & 7) << 4;
        unsigned char* xp = s_xe + p * 128;
        float tv = t[r * 129 + 1 + p];
        if (tid < 128) {
            #pragma unroll
            for (int cgi = 0; cgi < 2; ++cgi) {
                float x = s_od[cgi] + tv * s_od[cgi + 3];
                *(unsigned short*)(xp + ((2 * cgi) ^ psw)) = f2bf(x);
                float sv = sinf(x), cv = cosf(x);
                #pragma unroll
                for (int l = 0; l < 10; ++l) {
                    *(unsigned short*)(xp + ((2 * (3 + 6 * l + cgi)) ^ psw)) = f2bf(sv);
                    *(unsigned short*)(xp + ((2 * (6 + 6 * l + cgi)) ^ psw)) = f2bf(cv);
                    float ns = 2.f * sv * cv, nc = 1.f - 2.f * sv * sv;
                    sv = ns; cv = nc;
                }
            }
        } else {
            float x = s_od[2] + tv * s_od[5];
            *(unsigned short*)(xp + (4 ^ psw)) = f2bf(x);
            float sv = sinf(x), cv = cosf(x);
            #pragma unroll
            for (int l = 0; l < 10; ++l) {
                *(unsigned short*)(xp + ((2 * (5 + 6 * l)) ^ psw)) = f2bf(sv);
                *(unsigned short*)(xp + ((2 * (8 + 6 * l)) ^ psw)) = f2bf(cv);
                float ns = 2.f * sv * cv, nc = 1.f - 2.f * sv * sv;
                sv = ns; cv = nc;
            }
            *(unsigned short*)(xp + (126 ^ psw)) = 0;
            // decont[j] = bc1[j] + sum_k de[k]*Wc1[256+k][j]
            float acc = bc1g[p];
            for (int k = 0; k < 27; ++k)
                acc = fmaf(s_de[k], Wc1g[(256 + k) * 128 + p], acc);
            s_bias[768 + p] = acc;
        }
    }
    __syncthreads();

    // ======================= MLP (no barriers) =============================
    short8 BA[16], BB[16];
    float sp = 0.f, c0 = 0.f, c1 = 0.f, c2 = 0.f;

    // Layer 0 (K=64): B from s_xe, 8 tiles -> BA
    {
        short8 BX[4];
        #pragma unroll
        for (int ks = 0; ks < 4; ++ks)
            BX[ks] = *(const short8*)(s_xe + row * 128 + ((32 * ks + 16 * hi) ^ sw));
        #pragma unroll
        for (int ct = 0; ct < 8; ++ct) {
            const short8* __restrict__ ap = (const short8*)wt + (ct * 4) * 64 + lane;
            f32x16 acc;
            #pragma unroll
            for (int g = 0; g < 4; ++g) {
                f32x4 bv = *(const f32x4*)&s_bias[ct * 32 + 4 * hi + 8 * g];
                acc[4*g+0] = bv[0]; acc[4*g+1] = bv[1];
                acc[4*g+2] = bv[2]; acc[4*g+3] = bv[3];
            }
            #pragma unroll
            for (int ks = 0; ks < 4; ++ks)
                acc = MFMA32(ap[ks * 64], BX[ks], acc);
            float rr[16];
            #pragma unroll
            for (int i = 0; i < 16; ++i) rr[i] = fmaxf(acc[i], 0.f);
            BA[2*ct+0] = pack_half(rr[0], rr[1], rr[2],  rr[3],
                                   rr[4], rr[5], rr[6],  rr[7]);
            BA[2*ct+1] = pack_half(rr[8], rr[9], rr[10], rr[11],
                                   rr[12], rr[13], rr[14], rr[15]);
        }
    }

    // Layer 1: BA -> BB
    mlp_layer<8, false, true, false>(wt + 16384, s_bias + 256, nullptr, nullptr,
                                     lane, hi, BA, BB, sp, c0, c1, c2);
    // Layer 2: BB -> BA, sigma partial accumulated
    mlp_layer<8, true, true, false>(wt + 81920, s_bias + 512, s_ws, nullptr,
                                    lane, hi, BB, BA, sp, c0, c1, c2);
    // sigma finalize
    sp += __shfl_xor(sp, 32);
    if (lane < 32) {
        float x = sp + bsg[0];
        s_sigma[row] = fmaxf(x, 0.f) + log1pf(expf(-fabsf(x)));
    }
    // Wc1 (128 cols): BA -> color partials
    mlp_layer<4, false, false, true>(wt + 147456, s_bias + 768, nullptr, s_wc2R,
                                     lane, hi, BA, BB, sp, c0, c1, c2);
    c0 += __shfl_xor(c0, 32);
    c1 += __shfl_xor(c1, 32);
    c2 += __shfl_xor(c2, 32);
    if (lane < 32) {
        s_color[row * 3 + 0] = 1.f / (1.f + expf(-(c0 + bc2g[0])));
        s_color[row * 3 + 1] = 1.f / (1.f + expf(-(c1 + bc2g[1])));
        s_color[row * 3 + 2] = 1.f / (1.f + expf(-(c2 + bc2g[2])));
    }
    __syncthreads();

    // ======================= render (sort/scan/composite) ==================
    if (tid < 129) {
        float v = s_t[tid];
        int rank = 0;
        for (int j = 0; j < 129; ++j) {
            float u = s_t[j];
            rank += (u < v) || (u == v && j < tid);
        }
        s_ts[rank] = v;
    }
    __syncthreads();
    if (tid < 128) {
        float dt = s_ts[tid + 1] - s_ts[tid];
        float sd = s_sigma[tid] * dt;
        s_sdt[tid] = sd;
        s_cum[tid] = sd;
    }
    __syncthreads();
    for (int off = 1; off < 128; off <<= 1) {
        float add = (tid < 128 && tid >= off) ? s_cum[tid - off] : 0.f;
        __syncthreads();
        if (tid < 128) s_cum[tid] += add;
        __syncthreads();
    }
    if (tid < 128) {
        float Ti = (tid == 0) ? 1.f : expf(-s_cum[tid - 1]);
        float alpha = 1.f - expf(-s_sdt[tid]);
        float w = Ti * alpha;
        s_wi[tid] = w;
        wi_out[r * 128 + tid] = w;
    }
    __syncthreads();
    if (tid < 3) {
        float acc = 0.f;
        for (int i = 0; i < 128; ++i)
            acc = fmaf(s_wi[i], s_color[i * 3 + tid], acc);
        rgb_out[r * 3 + tid] = acc;
    }
}

extern "C" void kernel_launch(void* const* d_in, const int* in_sizes, int n_in,
                              void* d_out, int out_size, void* d_ws, size_t ws_size,
                              hipStream_t stream)
{
    const float* ray = (const float*)d_in[0];
    const float* t   = (const float*)d_in[1];
    const float* W0  = (const float*)d_in[2];
    const float* b0  = (const float*)d_in[3];
    const float* W1  = (const float*)d_in[4];
    const float* b1  = (const float*)d_in[5];
    const float* W2  = (const float*)d_in[6];
    const float* b2  = (const float*)d_in[7];
    const float* Ws  = (const float*)d_in[8];
    const float* bs  = (const float*)d_in[9];
    const float* Wc1 = (const float*)d_in[10];
    const float* bc1 = (const float*)d_in[11];
    const float* Wc2 = (const float*)d_in[12];
    const float* bc2 = (const float*)d_in[13];

    unsigned short* wt = (unsigned short*)d_ws;   // 360448 B fragment image
    float* rgb_out = (float*)d_out;               // R*3
    float* wi_out  = rgb_out + R_ * 3;            // R*128

    hipLaunchKernelGGL(prep_weights, dim3(704), dim3(256), 0, stream,
                       W0, W1, W2, Wc1, wt);
    hipLaunchKernelGGL(nerf_kernel, dim3(R_), dim3(256), 0, stream,
                       ray, t, b0, b1, b2, Ws, bs, Wc1, bc1, Wc2, bc2,
                       wt, rgb_out, wi_out);
}

// Round 9
// 349.234 us; speedup vs baseline: 2.1087x; 1.0079x over previous
//
#include <hip/hip_runtime.h>
#include <hip/hip_bf16.h>
#include <math.h>

constexpr int R_ = 4096;

typedef __attribute__((ext_vector_type(8))) short short8;
typedef __attribute__((ext_vector_type(4))) float f32x4;
typedef __attribute__((ext_vector_type(16))) float f32x16;
typedef __attribute__((ext_vector_type(2))) unsigned int uint2v;

#define MFMA32(a, b, c) __builtin_amdgcn_mfma_f32_32x32x16_bf16(a, b, c, 0, 0, 0)

union U4 { unsigned int u[4]; short8 s8; };

__device__ __forceinline__ unsigned short f2bf(float f) {
    unsigned int u = __float_as_uint(f);
    u += 0x7fffu + ((u >> 16) & 1u);   // RNE
    return (unsigned short)(u >> 16);
}

__device__ __forceinline__ unsigned int cvtpk(float lo, float hi) {
    unsigned int d;
    asm("v_cvt_pk_bf16_f32 %0, %1, %2" : "=v"(d) : "v"(lo), "v"(hi));
    return d;
}
// builtin (not raw asm): hazard recognizer must see permlane (round-5 lesson)
__device__ __forceinline__ void swap32(unsigned int& a, unsigned int& b) {
    uint2v r = __builtin_amdgcn_permlane32_swap(a, b, false, false);
    a = r[0]; b = r[1];
}

__device__ __forceinline__ short8 pack_half(float a0, float a1, float a2, float a3,
                                            float b0, float b1, float b2, float b3) {
    unsigned int x0 = cvtpk(a0, a1), x1 = cvtpk(a2, a3);
    unsigned int x2 = cvtpk(b0, b1), x3 = cvtpk(b2, b3);
    swap32(x0, x2);
    swap32(x1, x3);
    U4 t; t.u[0] = x0; t.u[1] = x1; t.u[2] = x2; t.u[3] = x3;
    return t.s8;
}

// ---------------------------------------------------------------------------
// Weight prep (UNCHANGED from round 6): bf16 fragments in MFMA order.
//   dst elem = base + ((ct*KS + ks)*64 + lane)*8 + j,  n = ct*32+ls,
//   k = ks*16 + hi*8 + j.  Regions: L0 @0 (KS=4), L1 @16384, L2 @81920,
//   Wc1 @147456 (all KS=16).
// ---------------------------------------------------------------------------
__global__ __launch_bounds__(256) void prep_weights(
    const float* __restrict__ W0, const float* __restrict__ W1,
    const float* __restrict__ W2, const float* __restrict__ Wc1,
    unsigned short* __restrict__ out)
{
    int i = blockIdx.x * 256 + threadIdx.x;
    if (i >= 180224) return;
    float val;
    if (i < 16384) {
        int j = i & 7, l = (i >> 3) & 63, q = i >> 9;
        int ks = q & 3, ct = q >> 2, ls = l & 31, hi = l >> 5;
        int n = ct * 32 + ls, k = ks * 16 + hi * 8 + j;
        val = (k < 63) ? W0[k * 256 + n] : 0.f;
    } else if (i < 81920) {
        int e = i - 16384;
        int j = e & 7, l = (e >> 3) & 63, q = e >> 9;
        int ks = q & 15, ct = q >> 4, ls = l & 31, hi = l >> 5;
        int n = ct * 32 + ls, k = ks * 16 + hi * 8 + j;
        val = W1[k * 256 + n];
    } else if (i < 147456) {
        int e = i - 81920;
        int j = e & 7, l = (e >> 3) & 63, q = e >> 9;
        int ks = q & 15, ct = q >> 4, ls = l & 31, hi = l >> 5;
        int n = ct * 32 + ls, k = ks * 16 + hi * 8 + j;
        val = W2[k * 256 + n];
    } else {
        int e = i - 147456;
        int j = e & 7, l = (e >> 3) & 63, q = e >> 9;
        int ks = q & 15, ct = q >> 4, ls = l & 31, hi = l >> 5;
        int n = ct * 32 + ls, k = ks * 16 + hi * 8 + j;
        val = Wc1[k * 128 + n];
    }
    out[i] = f2bf(val);
}

// Per-tile epilogue (identical math to round 6, factored out).
template <bool DO_SIGMA, bool DO_PACK, bool DO_COLOR>
__device__ __forceinline__ void epilog(
    const f32x16& acc, int ct,
    const float* __restrict__ wsv, const float* __restrict__ wc2R,
    int hi, short8* __restrict__ Bout,
    float& sp, float& c0, float& c1, float& c2)
{
    float rr[16];
    #pragma unroll
    for (int i = 0; i < 16; ++i) rr[i] = fmaxf(acc[i], 0.f);
    if constexpr (DO_SIGMA) {
        #pragma unroll
        for (int g = 0; g < 4; ++g) {
            f32x4 wv = *(const f32x4*)&wsv[ct * 32 + 4 * hi + 8 * g];
            sp = fmaf(rr[4*g+0], wv[0], sp);
            sp = fmaf(rr[4*g+1], wv[1], sp);
            sp = fmaf(rr[4*g+2], wv[2], sp);
            sp = fmaf(rr[4*g+3], wv[3], sp);
        }
    }
    if constexpr (DO_COLOR) {
        #pragma unroll
        for (int g = 0; g < 4; ++g) {
            int nb = ct * 32 + 4 * hi + 8 * g;
            f32x4 w0 = *(const f32x4*)&wc2R[0 * 128 + nb];
            f32x4 w1 = *(const f32x4*)&wc2R[1 * 128 + nb];
            f32x4 w2 = *(const f32x4*)&wc2R[2 * 128 + nb];
            #pragma unroll
            for (int i = 0; i < 4; ++i) {
                c0 = fmaf(rr[4*g+i], w0[i], c0);
                c1 = fmaf(rr[4*g+i], w1[i], c1);
                c2 = fmaf(rr[4*g+i], w2[i], c2);
            }
        }
    }
    if constexpr (DO_PACK) {
        Bout[2*ct+0] = pack_half(rr[0], rr[1], rr[2],  rr[3],
                                 rr[4], rr[5], rr[6],  rr[7]);
        Bout[2*ct+1] = pack_half(rr[8], rr[9], rr[10], rr[11],
                                 rr[12], rr[13], rr[14], rr[15]);
    }
}

// One K=256 layer; PAIRED output tiles: two independent accumulator chains
// and two independent A-load streams share one Bin -> 2x MLP/ILP per wave.
template <int NT, bool DO_SIGMA, bool DO_PACK, bool DO_COLOR>
__device__ __forceinline__ void mlp_layer(
    const unsigned short* __restrict__ wbase,
    const float* __restrict__ biasv,
    const float* __restrict__ wsv,
    const float* __restrict__ wc2R,
    int lane, int hi,
    const short8 (&Bin)[16], short8* __restrict__ Bout,
    float& sp, float& c0, float& c1, float& c2)
{
    #pragma unroll
    for (int cp = 0; cp < NT; cp += 2) {
        const int ct0 = cp, ct1 = cp + 1;
        const short8* __restrict__ ap0 = (const short8*)wbase + (ct0 * 16) * 64 + lane;
        const short8* __restrict__ ap1 = (const short8*)wbase + (ct1 * 16) * 64 + lane;
        f32x16 a0, a1;
        #pragma unroll
        for (int g = 0; g < 4; ++g) {
            f32x4 b0v = *(const f32x4*)&biasv[ct0 * 32 + 4 * hi + 8 * g];
            f32x4 b1v = *(const f32x4*)&biasv[ct1 * 32 + 4 * hi + 8 * g];
            a0[4*g+0]=b0v[0]; a0[4*g+1]=b0v[1]; a0[4*g+2]=b0v[2]; a0[4*g+3]=b0v[3];
            a1[4*g+0]=b1v[0]; a1[4*g+1]=b1v[1]; a1[4*g+2]=b1v[2]; a1[4*g+3]=b1v[3];
        }
        #pragma unroll
        for (int ks = 0; ks < 16; ++ks) {
            a0 = MFMA32(ap0[ks * 64], Bin[ks], a0);
            a1 = MFMA32(ap1[ks * 64], Bin[ks], a1);
        }
        epilog<DO_SIGMA, DO_PACK, DO_COLOR>(a0, ct0, wsv, wc2R, hi, Bout, sp, c0, c1, c2);
        epilog<DO_SIGMA, DO_PACK, DO_COLOR>(a1, ct1, wsv, wc2R, hi, Bout, sp, c0, c1, c2);
    }
}

// ---------------------------------------------------------------------------
// Fused NeRF: 1 block = 1 ray, 256 threads = 4 waves, wave = 32 samples.
// Acts in registers; weights direct from global (L1/L2); MLP barrier-free.
// ---------------------------------------------------------------------------
__global__ __launch_bounds__(256, 2) void nerf_kernel(
    const float* __restrict__ ray, const float* __restrict__ t,
    const float* __restrict__ b0g, const float* __restrict__ b1g,
    const float* __restrict__ b2g,
    const float* __restrict__ Wsg, const float* __restrict__ bsg,
    const float* __restrict__ Wc1g, const float* __restrict__ bc1g,
    const float* __restrict__ Wc2g, const float* __restrict__ bc2g,
    const unsigned short* __restrict__ wt,
    float* __restrict__ rgb_out, float* __restrict__ wi_out)
{
    __shared__ __align__(16) unsigned char s_xe[128 * 128];  // 16 KB posenc
    __shared__ __align__(16) float s_bias[896];  // b0|b1|b2|decont
    __shared__ __align__(16) float s_ws[256];
    __shared__ __align__(16) float s_wc2R[384];  // [c][128]
    __shared__ float s_sigma[128];
    __shared__ float s_color[384];
    __shared__ float s_de[27];
    __shared__ float s_od[6];
    __shared__ float s_t[129];
    __shared__ float s_ts[129];
    __shared__ float s_sdt[128];
    __shared__ float s_cum[128];
    __shared__ float s_wi[128];

    const int tid  = threadIdx.x;
    const int wv   = tid >> 6;
    const int lane = tid & 63;
    const int r    = blockIdx.x;
    const int ls   = lane & 31;
    const int hi   = lane >> 5;
    const int row  = wv * 32 + ls;      // this wave-lane's sample
    const int sw   = (ls & 7) << 4;

    if (tid < 6) s_od[tid] = ray[r * 6 + tid];
    __syncthreads();
    const float d0 = s_od[3], d1 = s_od[4], d2 = s_od[5];

    // ---- fills: biases, head weights, de, t ----
    s_bias[tid] = b0g[tid];
    s_bias[256 + tid] = b1g[tid];
    s_bias[512 + tid] = b2g[tid];
    s_ws[tid] = Wsg[tid];
    for (int i = tid; i < 384; i += 256) {
        int c = i >> 7, n = i & 127;
        s_wc2R[i] = Wc2g[n * 3 + c];
    }
    if (tid < 129) s_t[tid] = t[r * 129 + tid];
    if (tid < 27) {
        int f = tid; float v;
        if (f < 3) v = (f == 0) ? d0 : ((f == 1) ? d1 : d2);
        else {
            int q = f - 3, l = q / 6, rm = q % 6, c = rm % 3;
            float dc = (c == 0) ? d0 : ((c == 1) ? d1 : d2);
            float a = dc * (float)(1 << l);
            v = (rm < 3) ? sinf(a) : cosf(a);
        }
        s_de[f] = v;
    }
    __syncthreads();

    // ---- posenc(x,10) into s_xe (rows=sample, 64 bf16, XOR-swizzled) ------
    {
        const int p = tid & 127;
        const int psw = (p & 7) << 4;
        unsigned char* xp = s_xe + p * 128;
        float tv = t[r * 129 + 1 + p];
        if (tid < 128) {
            #pragma unroll
            for (int cgi = 0; cgi < 2; ++cgi) {
                float x = s_od[cgi] + tv * s_od[cgi + 3];
                *(unsigned short*)(xp + ((2 * cgi) ^ psw)) = f2bf(x);
                float sv = sinf(x), cv = cosf(x);
                #pragma unroll
                for (int l = 0; l < 10; ++l) {
                    *(unsigned short*)(xp + ((2 * (3 + 6 * l + cgi)) ^ psw)) = f2bf(sv);
                    *(unsigned short*)(xp + ((2 * (6 + 6 * l + cgi)) ^ psw)) = f2bf(cv);
                    float ns = 2.f * sv * cv, nc = 1.f - 2.f * sv * sv;
                    sv = ns; cv = nc;
                }
            }
        } else {
            float x = s_od[2] + tv * s_od[5];
            *(unsigned short*)(xp + (4 ^ psw)) = f2bf(x);
            float sv = sinf(x), cv = cosf(x);
            #pragma unroll
            for (int l = 0; l < 10; ++l) {
                *(unsigned short*)(xp + ((2 * (5 + 6 * l)) ^ psw)) = f2bf(sv);
                *(unsigned short*)(xp + ((2 * (8 + 6 * l)) ^ psw)) = f2bf(cv);
                float ns = 2.f * sv * cv, nc = 1.f - 2.f * sv * sv;
                sv = ns; cv = nc;
            }
            *(unsigned short*)(xp + (126 ^ psw)) = 0;
            // decont[j] = bc1[j] + sum_k de[k]*Wc1[256+k][j]
            float acc = bc1g[p];
            for (int k = 0; k < 27; ++k)
                acc = fmaf(s_de[k], Wc1g[(256 + k) * 128 + p], acc);
            s_bias[768 + p] = acc;
        }
    }
    __syncthreads();

    // ======================= MLP (no barriers) =============================
    short8 BA[16], BB[16];
    float sp = 0.f, c0 = 0.f, c1 = 0.f, c2 = 0.f;

    // Layer 0 (K=64): B from s_xe, 8 tiles (paired) -> BA
    {
        short8 BX[4];
        #pragma unroll
        for (int ks = 0; ks < 4; ++ks)
            BX[ks] = *(const short8*)(s_xe + row * 128 + ((32 * ks + 16 * hi) ^ sw));
        #pragma unroll
        for (int cp = 0; cp < 4; ++cp) {
            const int ct0 = 2 * cp, ct1 = 2 * cp + 1;
            const short8* __restrict__ ap0 = (const short8*)wt + (ct0 * 4) * 64 + lane;
            const short8* __restrict__ ap1 = (const short8*)wt + (ct1 * 4) * 64 + lane;
            f32x16 a0, a1;
            #pragma unroll
            for (int g = 0; g < 4; ++g) {
                f32x4 b0v = *(const f32x4*)&s_bias[ct0 * 32 + 4 * hi + 8 * g];
                f32x4 b1v = *(const f32x4*)&s_bias[ct1 * 32 + 4 * hi + 8 * g];
                a0[4*g+0]=b0v[0]; a0[4*g+1]=b0v[1]; a0[4*g+2]=b0v[2]; a0[4*g+3]=b0v[3];
                a1[4*g+0]=b1v[0]; a1[4*g+1]=b1v[1]; a1[4*g+2]=b1v[2]; a1[4*g+3]=b1v[3];
            }
            #pragma unroll
            for (int ks = 0; ks < 4; ++ks) {
                a0 = MFMA32(ap0[ks * 64], BX[ks], a0);
                a1 = MFMA32(ap1[ks * 64], BX[ks], a1);
            }
            epilog<false, true, false>(a0, ct0, nullptr, nullptr, hi, BA, sp, c0, c1, c2);
            epilog<false, true, false>(a1, ct1, nullptr, nullptr, hi, BA, sp, c0, c1, c2);
        }
    }

    // Layer 1: BA -> BB
    mlp_layer<8, false, true, false>(wt + 16384, s_bias + 256, nullptr, nullptr,
                                     lane, hi, BA, BB, sp, c0, c1, c2);
    // Layer 2: BB -> BA, sigma partial accumulated
    mlp_layer<8, true, true, false>(wt + 81920, s_bias + 512, s_ws, nullptr,
                                    lane, hi, BB, BA, sp, c0, c1, c2);
    // sigma finalize
    sp += __shfl_xor(sp, 32);
    if (lane < 32) {
        float x = sp + bsg[0];
        s_sigma[row] = fmaxf(x, 0.f) + log1pf(expf(-fabsf(x)));
    }
    // Wc1 (128 cols): BA -> color partials
    mlp_layer<4, false, false, true>(wt + 147456, s_bias + 768, nullptr, s_wc2R,
                                     lane, hi, BA, BB, sp, c0, c1, c2);
    c0 += __shfl_xor(c0, 32);
    c1 += __shfl_xor(c1, 32);
    c2 += __shfl_xor(c2, 32);
    if (lane < 32) {
        s_color[row * 3 + 0] = 1.f / (1.f + expf(-(c0 + bc2g[0])));
        s_color[row * 3 + 1] = 1.f / (1.f + expf(-(c1 + bc2g[1])));
        s_color[row * 3 + 2] = 1.f / (1.f + expf(-(c2 + bc2g[2])));
    }
    __syncthreads();

    // ======================= render (sort/scan/composite) ==================
    if (tid < 129) {
        float v = s_t[tid];
        int rank = 0;
        for (int j = 0; j < 129; ++j) {
            float u = s_t[j];
            rank += (u < v) || (u == v && j < tid);
        }
        s_ts[rank] = v;
    }
    __syncthreads();
    if (tid < 128) {
        float dt = s_ts[tid + 1] - s_ts[tid];
        float sd = s_sigma[tid] * dt;
        s_sdt[tid] = sd;
        s_cum[tid] = sd;
    }
    __syncthreads();
    for (int off = 1; off < 128; off <<= 1) {
        float add = (tid < 128 && tid >= off) ? s_cum[tid - off] : 0.f;
        __syncthreads();
        if (tid < 128) s_cum[tid] += add;
        __syncthreads();
    }
    if (tid < 128) {
        float Ti = (tid == 0) ? 1.f : expf(-s_cum[tid - 1]);
        float alpha = 1.f - expf(-s_sdt[tid]);
        float w = Ti * alpha;
        s_wi[tid] = w;
        wi_out[r * 128 + tid] = w;
    }
    __syncthreads();
    if (tid < 3) {
        float acc = 0.f;
        for (int i = 0; i < 128; ++i)
            acc = fmaf(s_wi[i], s_color[i * 3 + tid], acc);
        rgb_out[r * 3 + tid] = acc;
    }
}

extern "C" void kernel_launch(void* const* d_in, const int* in_sizes, int n_in,
                              void* d_out, int out_size, void* d_ws, size_t ws_size,
                              hipStream_t stream)
{
    const float* ray = (const float*)d_in[0];
    const float* t   = (const float*)d_in[1];
    const float* W0  = (const float*)d_in[2];
    const float* b0  = (const float*)d_in[3];
    const float* W1  = (const float*)d_in[4];
    const float* b1  = (const float*)d_in[5];
    const float* W2  = (const float*)d_in[6];
    const float* b2  = (const float*)d_in[7];
    const float* Ws  = (const float*)d_in[8];
    const float* bs  = (const float*)d_in[9];
    const float* Wc1 = (const float*)d_in[10];
    const float* bc1 = (const float*)d_in[11];
    const float* Wc2 = (const float*)d_in[12];
    const float* bc2 = (const float*)d_in[13];

    unsigned short* wt = (unsigned short*)d_ws;   // 360448 B fragment image
    float* rgb_out = (float*)d_out;               // R*3
    float* wi_out  = rgb_out + R_ * 3;            // R*128

    hipLaunchKernelGGL(prep_weights, dim3(704), dim3(256), 0, stream,
                       W0, W1, W2, Wc1, wt);
    hipLaunchKernelGGL(nerf_kernel, dim3(R_), dim3(256), 0, stream,
                       ray, t, b0, b1, b2, Ws, bs, Wc1, bc1, Wc2, bc2,
                       wt, rgb_out, wi_out);
}

// Round 10
// 229.769 us; speedup vs baseline: 3.2051x; 1.5199x over previous
//
#include <hip/hip_runtime.h>
#include <hip/hip_bf16.h>
#include <math.h>

constexpr int R_ = 4096;

typedef __attribute__((ext_vector_type(8))) short short8;
typedef __attribute__((ext_vector_type(4))) float f32x4;
typedef __attribute__((ext_vector_type(16))) float f32x16;
typedef __attribute__((ext_vector_type(2))) unsigned int uint2v;

#define MFMA32(a, b, c) __builtin_amdgcn_mfma_f32_32x32x16_bf16(a, b, c, 0, 0, 0)

union U4 { unsigned int u[4]; short8 s8; };

__device__ __forceinline__ unsigned short f2bf(float f) {
    unsigned int u = __float_as_uint(f);
    u += 0x7fffu + ((u >> 16) & 1u);   // RNE
    return (unsigned short)(u >> 16);
}

__device__ __forceinline__ unsigned int cvtpk(float lo, float hi) {
    unsigned int d;
    asm("v_cvt_pk_bf16_f32 %0, %1, %2" : "=v"(d) : "v"(lo), "v"(hi));
    return d;
}
// builtin (not raw asm): hazard recognizer must see permlane (round-5 lesson)
__device__ __forceinline__ void swap32(unsigned int& a, unsigned int& b) {
    uint2v r = __builtin_amdgcn_permlane32_swap(a, b, false, false);
    a = r[0]; b = r[1];
}

__device__ __forceinline__ short8 pack_half(float a0, float a1, float a2, float a3,
                                            float b0, float b1, float b2, float b3) {
    unsigned int x0 = cvtpk(a0, a1), x1 = cvtpk(a2, a3);
    unsigned int x2 = cvtpk(b0, b1), x3 = cvtpk(b2, b3);
    swap32(x0, x2);
    swap32(x1, x3);
    U4 t; t.u[0] = x0; t.u[1] = x1; t.u[2] = x2; t.u[3] = x3;
    return t.s8;
}

// ---------------------------------------------------------------------------
// Weight prep (UNCHANGED): bf16 fragments in MFMA order.
//   dst elem = base + ((ct*KS + ks)*64 + lane)*8 + j,  n = ct*32+ls,
//   k = ks*16 + hi*8 + j.  Regions: L0 @0 (KS=4), L1 @16384, L2 @81920,
//   Wc1 @147456 (all KS=16).
// ---------------------------------------------------------------------------
__global__ __launch_bounds__(256) void prep_weights(
    const float* __restrict__ W0, const float* __restrict__ W1,
    const float* __restrict__ W2, const float* __restrict__ Wc1,
    unsigned short* __restrict__ out)
{
    int i = blockIdx.x * 256 + threadIdx.x;
    if (i >= 180224) return;
    float val;
    if (i < 16384) {
        int j = i & 7, l = (i >> 3) & 63, q = i >> 9;
        int ks = q & 3, ct = q >> 2, ls = l & 31, hi = l >> 5;
        int n = ct * 32 + ls, k = ks * 16 + hi * 8 + j;
        val = (k < 63) ? W0[k * 256 + n] : 0.f;
    } else if (i < 81920) {
        int e = i - 16384;
        int j = e & 7, l = (e >> 3) & 63, q = e >> 9;
        int ks = q & 15, ct = q >> 4, ls = l & 31, hi = l >> 5;
        int n = ct * 32 + ls, k = ks * 16 + hi * 8 + j;
        val = W1[k * 256 + n];
    } else if (i < 147456) {
        int e = i - 81920;
        int j = e & 7, l = (e >> 3) & 63, q = e >> 9;
        int ks = q & 15, ct = q >> 4, ls = l & 31, hi = l >> 5;
        int n = ct * 32 + ls, k = ks * 16 + hi * 8 + j;
        val = W2[k * 256 + n];
    } else {
        int e = i - 147456;
        int j = e & 7, l = (e >> 3) & 63, q = e >> 9;
        int ks = q & 15, ct = q >> 4, ls = l & 31, hi = l >> 5;
        int n = ct * 32 + ls, k = ks * 16 + hi * 8 + j;
        val = Wc1[k * 128 + n];
    }
    out[i] = f2bf(val);
}

// Per-tile epilogue (identical math to rounds 6/9).
template <bool DO_SIGMA, bool DO_PACK, bool DO_COLOR>
__device__ __forceinline__ void epilog(
    const f32x16& acc, int ct,
    const float* __restrict__ wsv, const float* __restrict__ wc2R,
    int hi, short8* __restrict__ Bout,
    float& sp, float& c0, float& c1, float& c2)
{
    float rr[16];
    #pragma unroll
    for (int i = 0; i < 16; ++i) rr[i] = fmaxf(acc[i], 0.f);
    if constexpr (DO_SIGMA) {
        #pragma unroll
        for (int g = 0; g < 4; ++g) {
            f32x4 wv = *(const f32x4*)&wsv[ct * 32 + 4 * hi + 8 * g];
            sp = fmaf(rr[4*g+0], wv[0], sp);
            sp = fmaf(rr[4*g+1], wv[1], sp);
            sp = fmaf(rr[4*g+2], wv[2], sp);
            sp = fmaf(rr[4*g+3], wv[3], sp);
        }
    }
    if constexpr (DO_COLOR) {
        #pragma unroll
        for (int g = 0; g < 4; ++g) {
            int nb = ct * 32 + 4 * hi + 8 * g;
            f32x4 w0 = *(const f32x4*)&wc2R[0 * 128 + nb];
            f32x4 w1 = *(const f32x4*)&wc2R[1 * 128 + nb];
            f32x4 w2 = *(const f32x4*)&wc2R[2 * 128 + nb];
            #pragma unroll
            for (int i = 0; i < 4; ++i) {
                c0 = fmaf(rr[4*g+i], w0[i], c0);
                c1 = fmaf(rr[4*g+i], w1[i], c1);
                c2 = fmaf(rr[4*g+i], w2[i], c2);
            }
        }
    }
    if constexpr (DO_PACK) {
        Bout[2*ct+0] = pack_half(rr[0], rr[1], rr[2],  rr[3],
                                 rr[4], rr[5], rr[6],  rr[7]);
        Bout[2*ct+1] = pack_half(rr[8], rr[9], rr[10], rr[11],
                                 rr[12], rr[13], rr[14], rr[15]);
    }
}

// One K=256 layer; HALF-TILE PING-PONG A-PREFETCH: P1 (next 8 frags) loads
// issue before the 8 MFMAs on P0, so each load has >=8 MFMAs + epilogue of
// latency cover and the compiler emits counted vmcnt (not serial load->use).
// All indices static under full unroll.
template <int NT, bool DO_SIGMA, bool DO_PACK, bool DO_COLOR>
__device__ __forceinline__ void mlp_layer(
    const unsigned short* __restrict__ wbase,
    const float* __restrict__ biasv,
    const float* __restrict__ wsv,
    const float* __restrict__ wc2R,
    int lane, int hi,
    const short8 (&Bin)[16], short8* __restrict__ Bout,
    float& sp, float& c0, float& c1, float& c2)
{
    const short8* __restrict__ w = (const short8*)wbase + lane;
    short8 P0[8], P1[8];
    #pragma unroll
    for (int j = 0; j < 8; ++j) P0[j] = w[j * 64];          // tile0 ks0-7
    #pragma unroll
    for (int ct = 0; ct < NT; ++ct) {
        #pragma unroll
        for (int j = 0; j < 8; ++j)                          // this tile ks8-15
            P1[j] = w[(ct * 16 + 8 + j) * 64];
        f32x16 acc;
        #pragma unroll
        for (int g = 0; g < 4; ++g) {
            f32x4 bv = *(const f32x4*)&biasv[ct * 32 + 4 * hi + 8 * g];
            acc[4*g+0]=bv[0]; acc[4*g+1]=bv[1]; acc[4*g+2]=bv[2]; acc[4*g+3]=bv[3];
        }
        #pragma unroll
        for (int j = 0; j < 8; ++j) acc = MFMA32(P0[j], Bin[j], acc);
        if (ct + 1 < NT) {
            #pragma unroll
            for (int j = 0; j < 8; ++j)                      // next tile ks0-7
                P0[j] = w[((ct + 1) * 16 + j) * 64];
        }
        #pragma unroll
        for (int j = 0; j < 8; ++j) acc = MFMA32(P1[j], Bin[8 + j], acc);
        epilog<DO_SIGMA, DO_PACK, DO_COLOR>(acc, ct, wsv, wc2R, hi, Bout,
                                            sp, c0, c1, c2);
    }
}

// ---------------------------------------------------------------------------
// Fused NeRF: 1 block = 1 ray, 256 threads = 4 waves, wave = 32 samples.
// Acts in registers; weights direct from global (L1/L2); MLP barrier-free.
// ---------------------------------------------------------------------------
__global__ __launch_bounds__(256, 2) void nerf_kernel(
    const float* __restrict__ ray, const float* __restrict__ t,
    const float* __restrict__ b0g, const float* __restrict__ b1g,
    const float* __restrict__ b2g,
    const float* __restrict__ Wsg, const float* __restrict__ bsg,
    const float* __restrict__ Wc1g, const float* __restrict__ bc1g,
    const float* __restrict__ Wc2g, const float* __restrict__ bc2g,
    const unsigned short* __restrict__ wt,
    float* __restrict__ rgb_out, float* __restrict__ wi_out)
{
    __shared__ __align__(16) unsigned char s_xe[128 * 128];  // 16 KB posenc
    __shared__ __align__(16) float s_bias[896];  // b0|b1|b2|decont
    __shared__ __align__(16) float s_ws[256];
    __shared__ __align__(16) float s_wc2R[384];  // [c][128]
    __shared__ float s_sigma[128];
    __shared__ float s_color[384];
    __shared__ float s_de[27];
    __shared__ float s_od[6];
    __shared__ float s_t[129];
    __shared__ float s_ts[129];
    __shared__ float s_sdt[128];
    __shared__ float s_cum[128];
    __shared__ float s_wi[128];

    const int tid  = threadIdx.x;
    const int wv   = tid >> 6;
    const int lane = tid & 63;
    const int r    = blockIdx.x;
    const int ls   = lane & 31;
    const int hi   = lane >> 5;
    const int row  = wv * 32 + ls;      // this wave-lane's sample
    const int sw   = (ls & 7) << 4;

    if (tid < 6) s_od[tid] = ray[r * 6 + tid];
    __syncthreads();
    const float d0 = s_od[3], d1 = s_od[4], d2 = s_od[5];

    // ---- fills: biases, head weights, de, t ----
    s_bias[tid] = b0g[tid];
    s_bias[256 + tid] = b1g[tid];
    s_bias[512 + tid] = b2g[tid];
    s_ws[tid] = Wsg[tid];
    for (int i = tid; i < 384; i += 256) {
        int c = i >> 7, n = i & 127;
        s_wc2R[i] = Wc2g[n * 3 + c];
    }
    if (tid < 129) s_t[tid] = t[r * 129 + tid];
    if (tid < 27) {
        int f = tid; float v;
        if (f < 3) v = (f == 0) ? d0 : ((f == 1) ? d1 : d2);
        else {
            int q = f - 3, l = q / 6, rm = q % 6, c = rm % 3;
            float dc = (c == 0) ? d0 : ((c == 1) ? d1 : d2);
            float a = dc * (float)(1 << l);
            v = (rm < 3) ? sinf(a) : cosf(a);
        }
        s_de[f] = v;
    }
    __syncthreads();

    // ---- posenc(x,10) into s_xe (rows=sample, 64 bf16, XOR-swizzled) ------
    {
        const int p = tid & 127;
        const int psw = (p & 7) << 4;
        unsigned char* xp = s_xe + p * 128;
        float tv = t[r * 129 + 1 + p];
        if (tid < 128) {
            #pragma unroll
            for (int cgi = 0; cgi < 2; ++cgi) {
                float x = s_od[cgi] + tv * s_od[cgi + 3];
                *(unsigned short*)(xp + ((2 * cgi) ^ psw)) = f2bf(x);
                float sv = sinf(x), cv = cosf(x);
                #pragma unroll
                for (int l = 0; l < 10; ++l) {
                    *(unsigned short*)(xp + ((2 * (3 + 6 * l + cgi)) ^ psw)) = f2bf(sv);
                    *(unsigned short*)(xp + ((2 * (6 + 6 * l + cgi)) ^ psw)) = f2bf(cv);
                    float ns = 2.f * sv * cv, nc = 1.f - 2.f * sv * sv;
                    sv = ns; cv = nc;
                }
            }
        } else {
            float x = s_od[2] + tv * s_od[5];
            *(unsigned short*)(xp + (4 ^ psw)) = f2bf(x);
            float sv = sinf(x), cv = cosf(x);
            #pragma unroll
            for (int l = 0; l < 10; ++l) {
                *(unsigned short*)(xp + ((2 * (5 + 6 * l)) ^ psw)) = f2bf(sv);
                *(unsigned short*)(xp + ((2 * (8 + 6 * l)) ^ psw)) = f2bf(cv);
                float ns = 2.f * sv * cv, nc = 1.f - 2.f * sv * sv;
                sv = ns; cv = nc;
            }
            *(unsigned short*)(xp + (126 ^ psw)) = 0;
            // decont[j] = bc1[j] + sum_k de[k]*Wc1[256+k][j]
            float acc = bc1g[p];
            for (int k = 0; k < 27; ++k)
                acc = fmaf(s_de[k], Wc1g[(256 + k) * 128 + p], acc);
            s_bias[768 + p] = acc;
        }
    }
    __syncthreads();

    // ======================= MLP (no barriers) =============================
    short8 BA[16], BB[16];
    float sp = 0.f, c0 = 0.f, c1 = 0.f, c2 = 0.f;

    // Layer 0 (K=64): B from s_xe, 8 tiles, 4-frag ping-pong prefetch -> BA
    {
        short8 BX[4];
        #pragma unroll
        for (int ks = 0; ks < 4; ++ks)
            BX[ks] = *(const short8*)(s_xe + row * 128 + ((32 * ks + 16 * hi) ^ sw));
        const short8* __restrict__ w0 = (const short8*)wt + lane;
        short8 Q0[4], Q1[4];
        #pragma unroll
        for (int j = 0; j < 4; ++j) Q0[j] = w0[j * 64];
        #pragma unroll
        for (int ct = 0; ct < 8; ++ct) {
            if (ct + 1 < 8) {
                #pragma unroll
                for (int j = 0; j < 4; ++j)
                    Q1[j] = w0[((ct + 1) * 4 + j) * 64];
            }
            f32x16 acc;
            #pragma unroll
            for (int g = 0; g < 4; ++g) {
                f32x4 bv = *(const f32x4*)&s_bias[ct * 32 + 4 * hi + 8 * g];
                acc[4*g+0]=bv[0]; acc[4*g+1]=bv[1]; acc[4*g+2]=bv[2]; acc[4*g+3]=bv[3];
            }
            #pragma unroll
            for (int j = 0; j < 4; ++j) acc = MFMA32(Q0[j], BX[j], acc);
            epilog<false, true, false>(acc, ct, nullptr, nullptr, hi, BA,
                                       sp, c0, c1, c2);
            #pragma unroll
            for (int j = 0; j < 4; ++j) Q0[j] = Q1[j];   // renamed, unrolled
        }
    }

    // Layer 1: BA -> BB
    mlp_layer<8, false, true, false>(wt + 16384, s_bias + 256, nullptr, nullptr,
                                     lane, hi, BA, BB, sp, c0, c1, c2);
    // Layer 2: BB -> BA, sigma partial accumulated
    mlp_layer<8, true, true, false>(wt + 81920, s_bias + 512, s_ws, nullptr,
                                    lane, hi, BB, BA, sp, c0, c1, c2);
    // sigma finalize
    sp += __shfl_xor(sp, 32);
    if (lane < 32) {
        float x = sp + bsg[0];
        s_sigma[row] = fmaxf(x, 0.f) + log1pf(expf(-fabsf(x)));
    }
    // Wc1 (128 cols): BA -> color partials
    mlp_layer<4, false, false, true>(wt + 147456, s_bias + 768, nullptr, s_wc2R,
                                     lane, hi, BA, BB, sp, c0, c1, c2);
    c0 += __shfl_xor(c0, 32);
    c1 += __shfl_xor(c1, 32);
    c2 += __shfl_xor(c2, 32);
    if (lane < 32) {
        s_color[row * 3 + 0] = 1.f / (1.f + expf(-(c0 + bc2g[0])));
        s_color[row * 3 + 1] = 1.f / (1.f + expf(-(c1 + bc2g[1])));
        s_color[row * 3 + 2] = 1.f / (1.f + expf(-(c2 + bc2g[2])));
    }
    __syncthreads();

    // ======================= render (sort/scan/composite) ==================
    if (tid < 129) {
        float v = s_t[tid];
        int rank = 0;
        for (int j = 0; j < 129; ++j) {
            float u = s_t[j];
            rank += (u < v) || (u == v && j < tid);
        }
        s_ts[rank] = v;
    }
    __syncthreads();
    if (tid < 128) {
        float dt = s_ts[tid + 1] - s_ts[tid];
        float sd = s_sigma[tid] * dt;
        s_sdt[tid] = sd;
        s_cum[tid] = sd;
    }
    __syncthreads();
    for (int off = 1; off < 128; off <<= 1) {
        float add = (tid < 128 && tid >= off) ? s_cum[tid - off] : 0.f;
        __syncthreads();
        if (tid < 128) s_cum[tid] += add;
        __syncthreads();
    }
    if (tid < 128) {
        float Ti = (tid == 0) ? 1.f : expf(-s_cum[tid - 1]);
        float alpha = 1.f - expf(-s_sdt[tid]);
        float w = Ti * alpha;
        s_wi[tid] = w;
        wi_out[r * 128 + tid] = w;
    }
    __syncthreads();
    if (tid < 3) {
        float acc = 0.f;
        for (int i = 0; i < 128; ++i)
            acc = fmaf(s_wi[i], s_color[i * 3 + tid], acc);
        rgb_out[r * 3 + tid] = acc;
    }
}

extern "C" void kernel_launch(void* const* d_in, const int* in_sizes, int n_in,
                              void* d_out, int out_size, void* d_ws, size_t ws_size,
                              hipStream_t stream)
{
    const float* ray = (const float*)d_in[0];
    const float* t   = (const float*)d_in[1];
    const float* W0  = (const float*)d_in[2];
    const float* b0  = (const float*)d_in[3];
    const float* W1  = (const float*)d_in[4];
    const float* b1  = (const float*)d_in[5];
    const float* W2  = (const float*)d_in[6];
    const float* b2  = (const float*)d_in[7];
    const float* Ws  = (const float*)d_in[8];
    const float* bs  = (const float*)d_in[9];
    const float* Wc1 = (const float*)d_in[10];
    const float* bc1 = (const float*)d_in[11];
    const float* Wc2 = (const float*)d_in[12];
    const float* bc2 = (const float*)d_in[13];

    unsigned short* wt = (unsigned short*)d_ws;   // 360448 B fragment image
    float* rgb_out = (float*)d_out;               // R*3
    float* wi_out  = rgb_out + R_ * 3;            // R*128

    hipLaunchKernelGGL(prep_weights, dim3(704), dim3(256), 0, stream,
                       W0, W1, W2, Wc1, wt);
    hipLaunchKernelGGL(nerf_kernel, dim3(R_), dim3(256), 0, stream,
                       ray, t, b0, b1, b2, Ws, bs, Wc1, bc1, Wc2, bc2,
                       wt, rgb_out, wi_out);
}

// Round 12
// 216.979 us; speedup vs baseline: 3.3940x; 1.0589x over previous
//
#include <hip/hip_runtime.h>
#include <hip/hip_bf16.h>
#include <math.h>

constexpr int R_ = 4096;

typedef __attribute__((ext_vector_type(8))) short short8;
typedef __attribute__((ext_vector_type(4))) float f32x4;
typedef __attribute__((ext_vector_type(16))) float f32x16;
typedef __attribute__((ext_vector_type(2))) unsigned int uint2v;

#define MFMA32(a, b, c) __builtin_amdgcn_mfma_f32_32x32x16_bf16(a, b, c, 0, 0, 0)

union U4 { unsigned int u[4]; short8 s8; };

__device__ __forceinline__ unsigned short f2bf(float f) {
    unsigned int u = __float_as_uint(f);
    u += 0x7fffu + ((u >> 16) & 1u);   // RNE
    return (unsigned short)(u >> 16);
}

__device__ __forceinline__ unsigned int cvtpk(float lo, float hi) {
    unsigned int d;
    asm("v_cvt_pk_bf16_f32 %0, %1, %2" : "=v"(d) : "v"(lo), "v"(hi));
    return d;
}
// builtin (not raw asm): hazard recognizer must see permlane (round-5 lesson)
__device__ __forceinline__ void swap32(unsigned int& a, unsigned int& b) {
    uint2v r = __builtin_amdgcn_permlane32_swap(a, b, false, false);
    a = r[0]; b = r[1];
}

__device__ __forceinline__ short8 pack_half(float a0, float a1, float a2, float a3,
                                            float b0, float b1, float b2, float b3) {
    unsigned int x0 = cvtpk(a0, a1), x1 = cvtpk(a2, a3);
    unsigned int x2 = cvtpk(b0, b1), x3 = cvtpk(b2, b3);
    swap32(x0, x2);
    swap32(x1, x3);
    U4 t; t.u[0] = x0; t.u[1] = x1; t.u[2] = x2; t.u[3] = x3;
    return t.s8;
}

// ---------------------------------------------------------------------------
// Weight prep (UNCHANGED): bf16 fragments in MFMA order.
//   dst elem = base + ((ct*KS + ks)*64 + lane)*8 + j,  n = ct*32+ls,
//   k = ks*16 + hi*8 + j.  Regions: L0 @0 (KS=4), L1 @16384, L2 @81920,
//   Wc1 @147456 (all KS=16).
// ---------------------------------------------------------------------------
__global__ __launch_bounds__(256) void prep_weights(
    const float* __restrict__ W0, const float* __restrict__ W1,
    const float* __restrict__ W2, const float* __restrict__ Wc1,
    unsigned short* __restrict__ out)
{
    int i = blockIdx.x * 256 + threadIdx.x;
    if (i >= 180224) return;
    float val;
    if (i < 16384) {
        int j = i & 7, l = (i >> 3) & 63, q = i >> 9;
        int ks = q & 3, ct = q >> 2, ls = l & 31, hi = l >> 5;
        int n = ct * 32 + ls, k = ks * 16 + hi * 8 + j;
        val = (k < 63) ? W0[k * 256 + n] : 0.f;
    } else if (i < 81920) {
        int e = i - 16384;
        int j = e & 7, l = (e >> 3) & 63, q = e >> 9;
        int ks = q & 15, ct = q >> 4, ls = l & 31, hi = l >> 5;
        int n = ct * 32 + ls, k = ks * 16 + hi * 8 + j;
        val = W1[k * 256 + n];
    } else if (i < 147456) {
        int e = i - 81920;
        int j = e & 7, l = (e >> 3) & 63, q = e >> 9;
        int ks = q & 15, ct = q >> 4, ls = l & 31, hi = l >> 5;
        int n = ct * 32 + ls, k = ks * 16 + hi * 8 + j;
        val = W2[k * 256 + n];
    } else {
        int e = i - 147456;
        int j = e & 7, l = (e >> 3) & 63, q = e >> 9;
        int ks = q & 15, ct = q >> 4, ls = l & 31, hi = l >> 5;
        int n = ct * 32 + ls, k = ks * 16 + hi * 8 + j;
        val = Wc1[k * 128 + n];
    }
    out[i] = f2bf(val);
}

// Per-tile epilogue (identical math to green rounds 6/9/10).
template <bool DO_SIGMA, bool DO_PACK, bool DO_COLOR>
__device__ __forceinline__ void epilog(
    const f32x16& acc, int ct,
    const float* __restrict__ wsv, const float* __restrict__ wc2R,
    int hi, short8* __restrict__ Bout,
    float& sp, float& c0, float& c1, float& c2)
{
    float rr[16];
    #pragma unroll
    for (int i = 0; i < 16; ++i) rr[i] = fmaxf(acc[i], 0.f);
    if constexpr (DO_SIGMA) {
        #pragma unroll
        for (int g = 0; g < 4; ++g) {
            f32x4 wv = *(const f32x4*)&wsv[ct * 32 + 4 * hi + 8 * g];
            sp = fmaf(rr[4*g+0], wv[0], sp);
            sp = fmaf(rr[4*g+1], wv[1], sp);
            sp = fmaf(rr[4*g+2], wv[2], sp);
            sp = fmaf(rr[4*g+3], wv[3], sp);
        }
    }
    if constexpr (DO_COLOR) {
        #pragma unroll
        for (int g = 0; g < 4; ++g) {
            int nb = ct * 32 + 4 * hi + 8 * g;
            f32x4 w0 = *(const f32x4*)&wc2R[0 * 128 + nb];
            f32x4 w1 = *(const f32x4*)&wc2R[1 * 128 + nb];
            f32x4 w2 = *(const f32x4*)&wc2R[2 * 128 + nb];
            #pragma unroll
            for (int i = 0; i < 4; ++i) {
                c0 = fmaf(rr[4*g+i], w0[i], c0);
                c1 = fmaf(rr[4*g+i], w1[i], c1);
                c2 = fmaf(rr[4*g+i], w2[i], c2);
            }
        }
    }
    if constexpr (DO_PACK) {
        Bout[2*ct+0] = pack_half(rr[0], rr[1], rr[2],  rr[3],
                                 rr[4], rr[5], rr[6],  rr[7]);
        Bout[2*ct+1] = pack_half(rr[8], rr[9], rr[10], rr[11],
                                 rr[12], rr[13], rr[14], rr[15]);
    }
}

// One K=256 layer; ROLLING 4-FRAGMENT WINDOW (A/B4 ping-pong, 32 VGPR) keeps
// ~4-8 loads in flight with each group covered by 4 MFMAs.  Per-tile
// __syncthreads() re-aligns the 4 waves so they stream the same 16 KB tile
// through L1 together (3/4 of weight reads become L1 hits).  Full unroll
// keeps all register-array indices static (rule #20).
template <int NT, bool DO_SIGMA, bool DO_PACK, bool DO_COLOR>
__device__ __forceinline__ void mlp_layer(
    const unsigned short* __restrict__ wbase,
    const float* __restrict__ biasv,
    const float* __restrict__ wsv,
    const float* __restrict__ wc2R,
    int lane, int hi,
    const short8 (&Bin)[16], short8* __restrict__ Bout,
    float& sp, float& c0, float& c1, float& c2)
{
    const short8* __restrict__ w = (const short8*)wbase + lane;
    short8 A[4], B4[4];
    #pragma unroll
    for (int j = 0; j < 4; ++j) A[j] = w[j * 64];            // tile0 ks0-3
    #pragma unroll
    for (int ct = 0; ct < NT; ++ct) {
        f32x16 acc;
        #pragma unroll
        for (int g = 0; g < 4; ++g) {
            f32x4 bv = *(const f32x4*)&biasv[ct * 32 + 4 * hi + 8 * g];
            acc[4*g+0]=bv[0]; acc[4*g+1]=bv[1]; acc[4*g+2]=bv[2]; acc[4*g+3]=bv[3];
        }
        #pragma unroll
        for (int j = 0; j < 4; ++j) B4[j] = w[(ct * 16 + 4 + j) * 64];
        #pragma unroll
        for (int j = 0; j < 4; ++j) acc = MFMA32(A[j], Bin[j], acc);
        #pragma unroll
        for (int j = 0; j < 4; ++j) A[j] = w[(ct * 16 + 8 + j) * 64];
        #pragma unroll
        for (int j = 0; j < 4; ++j) acc = MFMA32(B4[j], Bin[4 + j], acc);
        #pragma unroll
        for (int j = 0; j < 4; ++j) B4[j] = w[(ct * 16 + 12 + j) * 64];
        #pragma unroll
        for (int j = 0; j < 4; ++j) acc = MFMA32(A[j], Bin[8 + j], acc);
        if (ct + 1 < NT) {
            #pragma unroll
            for (int j = 0; j < 4; ++j) A[j] = w[((ct + 1) * 16 + j) * 64];
        }
        #pragma unroll
        for (int j = 0; j < 4; ++j) acc = MFMA32(B4[j], Bin[12 + j], acc);
        epilog<DO_SIGMA, DO_PACK, DO_COLOR>(acc, ct, wsv, wc2R, hi, Bout,
                                            sp, c0, c1, c2);
        __syncthreads();   // wave-align for L1 reuse of the weight stream
    }
}

// ---------------------------------------------------------------------------
// Fused NeRF: 1 block = 1 ray, 256 threads = 4 waves, wave = 32 samples.
// Acts in registers; weights direct from global (L1/L2).
// ---------------------------------------------------------------------------
__global__ __launch_bounds__(256, 2) void nerf_kernel(
    const float* __restrict__ ray, const float* __restrict__ t,
    const float* __restrict__ b0g, const float* __restrict__ b1g,
    const float* __restrict__ b2g,
    const float* __restrict__ Wsg, const float* __restrict__ bsg,
    const float* __restrict__ Wc1g, const float* __restrict__ bc1g,
    const float* __restrict__ Wc2g, const float* __restrict__ bc2g,
    const unsigned short* __restrict__ wt,
    float* __restrict__ rgb_out, float* __restrict__ wi_out)
{
    __shared__ __align__(16) unsigned char s_xe[128 * 128];  // 16 KB posenc
    __shared__ __align__(16) float s_bias[896];  // b0|b1|b2|decont
    __shared__ __align__(16) float s_ws[256];
    __shared__ __align__(16) float s_wc2R[384];  // [c][128]
    __shared__ float s_sigma[128];
    __shared__ float s_color[384];
    __shared__ float s_de[27];
    __shared__ float s_od[6];
    __shared__ float s_t[129];
    __shared__ float s_ts[129];
    __shared__ float s_sdt[128];
    __shared__ float s_cum[128];
    __shared__ float s_wi[128];

    const int tid  = threadIdx.x;
    const int wv   = tid >> 6;
    const int lane = tid & 63;
    const int r    = blockIdx.x;
    const int ls   = lane & 31;
    const int hi   = lane >> 5;
    const int row  = wv * 32 + ls;      // this wave-lane's sample
    const int sw   = (ls & 7) << 4;

    if (tid < 6) s_od[tid] = ray[r * 6 + tid];
    __syncthreads();
    const float d0 = s_od[3], d1 = s_od[4], d2 = s_od[5];

    // ---- fills: biases, head weights, de, t ----
    s_bias[tid] = b0g[tid];
    s_bias[256 + tid] = b1g[tid];
    s_bias[512 + tid] = b2g[tid];
    s_ws[tid] = Wsg[tid];
    for (int i = tid; i < 384; i += 256) {
        int c = i >> 7, n = i & 127;
        s_wc2R[i] = Wc2g[n * 3 + c];
    }
    if (tid < 129) s_t[tid] = t[r * 129 + tid];
    if (tid < 27) {
        int f = tid; float v;
        if (f < 3) v = (f == 0) ? d0 : ((f == 1) ? d1 : d2);
        else {
            int q = f - 3, l = q / 6, rm = q % 6, c = rm % 3;
            float dc = (c == 0) ? d0 : ((c == 1) ? d1 : d2);
            float a = dc * (float)(1 << l);
            v = (rm < 3) ? sinf(a) : cosf(a);
        }
        s_de[f] = v;
    }
    __syncthreads();

    // ---- posenc(x,10) into s_xe (rows=sample, 64 bf16, XOR-swizzled) ------
    {
        const int p = tid & 127;
        const int psw = (p & 7) << 4;
        unsigned char* xp = s_xe + p * 128;
        float tv = t[r * 129 + 1 + p];
        if (tid < 128) {
            #pragma unroll
            for (int cgi = 0; cgi < 2; ++cgi) {
                float x = s_od[cgi] + tv * s_od[cgi + 3];
                *(unsigned short*)(xp + ((2 * cgi) ^ psw)) = f2bf(x);
                float sv = sinf(x), cv = cosf(x);
                #pragma unroll
                for (int l = 0; l < 10; ++l) {
                    *(unsigned short*)(xp + ((2 * (3 + 6 * l + cgi)) ^ psw)) = f2bf(sv);
                    *(unsigned short*)(xp + ((2 * (6 + 6 * l + cgi)) ^ psw)) = f2bf(cv);
                    float ns = 2.f * sv * cv, nc = 1.f - 2.f * sv * sv;
                    sv = ns; cv = nc;
                }
            }
        } else {
            float x = s_od[2] + tv * s_od[5];
            *(unsigned short*)(xp + (4 ^ psw)) = f2bf(x);
            float sv = sinf(x), cv = cosf(x);
            #pragma unroll
            for (int l = 0; l < 10; ++l) {
                *(unsigned short*)(xp + ((2 * (5 + 6 * l)) ^ psw)) = f2bf(sv);
                *(unsigned short*)(xp + ((2 * (8 + 6 * l)) ^ psw)) = f2bf(cv);
                float ns = 2.f * sv * cv, nc = 1.f - 2.f * sv * sv;
                sv = ns; cv = nc;
            }
            *(unsigned short*)(xp + (126 ^ psw)) = 0;
            // decont[j] = bc1[j] + sum_k de[k]*Wc1[256+k][j]
            float acc = bc1g[p];
            for (int k = 0; k < 27; ++k)
                acc = fmaf(s_de[k], Wc1g[(256 + k) * 128 + p], acc);
            s_bias[768 + p] = acc;
        }
    }
    __syncthreads();

    // ======================= MLP ===========================================
    short8 BA[16], BB[16];
    float sp = 0.f, c0 = 0.f, c1 = 0.f, c2 = 0.f;

    // Layer 0 (K=64): B from s_xe, 8 tiles, 4-frag ping-pong prefetch -> BA
    {
        short8 BX[4];
        #pragma unroll
        for (int ks = 0; ks < 4; ++ks)
            BX[ks] = *(const short8*)(s_xe + row * 128 + ((32 * ks + 16 * hi) ^ sw));
        const short8* __restrict__ w0 = (const short8*)wt + lane;
        short8 Q0[4], Q1[4];
        #pragma unroll
        for (int j = 0; j < 4; ++j) Q0[j] = w0[j * 64];
        #pragma unroll
        for (int ct = 0; ct < 8; ++ct) {
            if (ct + 1 < 8) {
                #pragma unroll
                for (int j = 0; j < 4; ++j)
                    Q1[j] = w0[((ct + 1) * 4 + j) * 64];
            }
            f32x16 acc;
            #pragma unroll
            for (int g = 0; g < 4; ++g) {
                f32x4 bv = *(const f32x4*)&s_bias[ct * 32 + 4 * hi + 8 * g];
                acc[4*g+0]=bv[0]; acc[4*g+1]=bv[1]; acc[4*g+2]=bv[2]; acc[4*g+3]=bv[3];
            }
            #pragma unroll
            for (int j = 0; j < 4; ++j) acc = MFMA32(Q0[j], BX[j], acc);
            epilog<false, true, false>(acc, ct, nullptr, nullptr, hi, BA,
                                       sp, c0, c1, c2);
            #pragma unroll
            for (int j = 0; j < 4; ++j) Q0[j] = Q1[j];   // renamed, unrolled
        }
    }

    // Layer 1: BA -> BB
    mlp_layer<8, false, true, false>(wt + 16384, s_bias + 256, nullptr, nullptr,
                                     lane, hi, BA, BB, sp, c0, c1, c2);
    // Layer 2: BB -> BA, sigma partial accumulated
    mlp_layer<8, true, true, false>(wt + 81920, s_bias + 512, s_ws, nullptr,
                                    lane, hi, BB, BA, sp, c0, c1, c2);
    // sigma finalize
    sp += __shfl_xor(sp, 32);
    if (lane < 32) {
        float x = sp + bsg[0];
        s_sigma[row] = fmaxf(x, 0.f) + log1pf(expf(-fabsf(x)));
    }
    // Wc1 (128 cols): BA -> color partials
    mlp_layer<4, false, false, true>(wt + 147456, s_bias + 768, nullptr, s_wc2R,
                                     lane, hi, BA, BB, sp, c0, c1, c2);
    c0 += __shfl_xor(c0, 32);
    c1 += __shfl_xor(c1, 32);
    c2 += __shfl_xor(c2, 32);
    if (lane < 32) {
        s_color[row * 3 + 0] = 1.f / (1.f + expf(-(c0 + bc2g[0])));
        s_color[row * 3 + 1] = 1.f / (1.f + expf(-(c1 + bc2g[1])));
        s_color[row * 3 + 2] = 1.f / (1.f + expf(-(c2 + bc2g[2])));
    }
    __syncthreads();

    // ======================= render (sort/scan/composite) ==================
    if (tid < 129) {
        float v = s_t[tid];
        int rank = 0;
        for (int j = 0; j < 129; ++j) {
            float u = s_t[j];
            rank += (u < v) || (u == v && j < tid);
        }
        s_ts[rank] = v;
    }
    __syncthreads();
    if (tid < 128) {
        float dt = s_ts[tid + 1] - s_ts[tid];
        float sd = s_sigma[tid] * dt;
        s_sdt[tid] = sd;
        s_cum[tid] = sd;
    }
    __syncthreads();
    for (int off = 1; off < 128; off <<= 1) {
        float add = (tid < 128 && tid >= off) ? s_cum[tid - off] : 0.f;
        __syncthreads();
        if (tid < 128) s_cum[tid] += add;
        __syncthreads();
    }
    if (tid < 128) {
        float Ti = (tid == 0) ? 1.f : expf(-s_cum[tid - 1]);
        float alpha = 1.f - expf(-s_sdt[tid]);
        float w = Ti * alpha;
        s_wi[tid] = w;
        wi_out[r * 128 + tid] = w;
    }
    __syncthreads();
    if (tid < 3) {
        float acc = 0.f;
        for (int i = 0; i < 128; ++i)
            acc = fmaf(s_wi[i], s_color[i * 3 + tid], acc);
        rgb_out[r * 3 + tid] = acc;
    }
}

extern "C" void kernel_launch(void* const* d_in, const int* in_sizes, int n_in,
                              void* d_out, int out_size, void* d_ws, size_t ws_size,
                              hipStream_t stream)
{
    const float* ray = (const float*)d_in[0];
    const float* t   = (const float*)d_in[1];
    const float* W0  = (const float*)d_in[2];
    const float* b0  = (const float*)d_in[3];
    const float* W1  = (const float*)d_in[4];
    const float* b1  = (const float*)d_in[5];
    const float* W2  = (const float*)d_in[6];
    const float* b2  = (const float*)d_in[7];
    const float* Ws  = (const float*)d_in[8];
    const float* bs  = (const float*)d_in[9];
    const float* Wc1 = (const float*)d_in[10];
    const float* bc1 = (const float*)d_in[11];
    const float* Wc2 = (const float*)d_in[12];
    const float* bc2 = (const float*)d_in[13];

    unsigned short* wt = (unsigned short*)d_ws;   // 360448 B fragment image
    float* rgb_out = (float*)d_out;               // R*3
    float* wi_out  = rgb_out + R_ * 3;            // R*128

    hipLaunchKernelGGL(prep_weights, dim3(704), dim3(256), 0, stream,
                       W0, W1, W2, Wc1, wt);
    hipLaunchKernelGGL(nerf_kernel, dim3(R_), dim3(256), 0, stream,
                       ray, t, b0, b1, b2, Ws, bs, Wc1, bc1, Wc2, bc2,
                       wt, rgb_out, wi_out);
}